// Round 9
// baseline (108.842 us; speedup 1.0000x reference)
//
#include <hip/hip_runtime.h>

#define KK 8
#define CC 16

typedef int   vint4   __attribute__((ext_vector_type(4)));
typedef float vfloat4 __attribute__((ext_vector_type(4)));
typedef unsigned int vuint4 __attribute__((ext_vector_type(4)));

// Record: 20B = 16 x i8 features + meta dword {bf16 inv_r2 | bf16 scale<<16}.
// 3 records per 64B line (60B + 4B pad): a record NEVER straddles a line.
static __device__ __forceinline__ unsigned int rec_base(int p) {
    int grp = p / 3;          // magic-mul
    int lane = p - grp * 3;
    return (unsigned int)grp * 64u + (unsigned int)lane * 20u;
}

static __device__ __forceinline__ unsigned short f32_to_bf16(float x) {
    unsigned int b = __float_as_uint(x);
    unsigned int r = b + 0x7FFFu + ((b >> 16) & 1u);
    return (unsigned short)(r >> 16);
}

// ---- Pass 1 (only prep pass): per-point scale + quantize + pack ----
__global__ void prep_kernel(const float* __restrict__ f,
                            const float* __restrict__ radii,
                            char* __restrict__ tab, int P) {
    int p = blockIdx.x * blockDim.x + threadIdx.x;
    if (p >= P) return;
    float v[CC];
    float am = 1e-20f;
#pragma unroll
    for (int c = 0; c < CC; ++c) {
        v[c] = f[(size_t)c * P + p];
        am = fmaxf(am, fabsf(v[c]));
    }
    unsigned short sc_b = f32_to_bf16(am * (1.0f / 127.0f));
    float s = __uint_as_float((unsigned int)sc_b << 16);
    float qs = 1.0f / s;
    unsigned int w[4];
#pragma unroll
    for (int j = 0; j < 4; ++j) {
        int q0 = __float2int_rn(v[4 * j + 0] * qs); q0 = max(-127, min(127, q0));
        int q1 = __float2int_rn(v[4 * j + 1] * qs); q1 = max(-127, min(127, q1));
        int q2 = __float2int_rn(v[4 * j + 2] * qs); q2 = max(-127, min(127, q2));
        int q3 = __float2int_rn(v[4 * j + 3] * qs); q3 = max(-127, min(127, q3));
        w[j] = ((unsigned int)q0 & 0xFFu) | (((unsigned int)q1 & 0xFFu) << 8) |
               (((unsigned int)q2 & 0xFFu) << 16) | (((unsigned int)q3 & 0xFFu) << 24);
    }
    float r = radii[p];
    unsigned short ir2_b = f32_to_bf16(1.0f / (r * r));
    unsigned int meta = (unsigned int)ir2_b | ((unsigned int)sc_b << 16);
    char* rec = tab + rec_base(p);
    *(unsigned int*)(rec + 0) = w[0];
    *(unsigned int*)(rec + 4) = w[1];
    *(unsigned int*)(rec + 8) = w[2];
    *(unsigned int*)(rec + 12) = w[3];
    *(unsigned int*)(rec + 16) = meta;
}

// ---- Pass 2: render. Lane-pair (h=0,1) processes TWO pixels; lane h owns
// channels [8h, 8h+8). 16 gathers in flight per thread (2x the ILP of one
// pixel), compiler-scheduled waits. Gather k: dwordx4 at rec+8h:
//   h=0: bytes 0-15 -> ch0-7 ; h=1: bytes 8-23 -> ch8-15 + meta in .z
__global__ void render_kernel(const int* __restrict__ idx,
                              const float* __restrict__ dists,
                              const char* __restrict__ tab,
                              float* __restrict__ out, int npix) {
    int tid = blockIdx.x * blockDim.x + threadIdx.x;
    int pp = tid >> 1;       // pixel-pair index
    int h = tid & 1;
    int px0 = pp * 2;
    if (px0 >= npix) return;
    int px1 = px0 + 1;

    // streams for both pixels (nt: read-once)
    const vint4* ipa = (const vint4*)(idx + (size_t)px0 * KK);
    const vfloat4* dpa = (const vfloat4*)(dists + (size_t)px0 * KK);
    const vint4* ipb = (const vint4*)(idx + (size_t)px1 * KK);
    const vfloat4* dpb = (const vfloat4*)(dists + (size_t)px1 * KK);
    vint4 ia0 = __builtin_nontemporal_load(ipa);
    vint4 ia1 = __builtin_nontemporal_load(ipa + 1);
    vint4 ib0 = __builtin_nontemporal_load(ipb);
    vint4 ib1 = __builtin_nontemporal_load(ipb + 1);
    vfloat4 da0 = __builtin_nontemporal_load(dpa);
    vfloat4 da1 = __builtin_nontemporal_load(dpa + 1);
    vfloat4 db0 = __builtin_nontemporal_load(dpb);
    vfloat4 db1 = __builtin_nontemporal_load(dpb + 1);

    int idsA[KK] = {ia0.x, ia0.y, ia0.z, ia0.w, ia1.x, ia1.y, ia1.z, ia1.w};
    int idsB[KK] = {ib0.x, ib0.y, ib0.z, ib0.w, ib1.x, ib1.y, ib1.z, ib1.w};
    float dsA[KK] = {da0.x, da0.y, da0.z, da0.w, da1.x, da1.y, da1.z, da1.w};
    float dsB[KK] = {db0.x, db0.y, db0.z, db0.w, db1.x, db1.y, db1.z, db1.w};

    vuint4 pkA[KK], pkB[KK];
    float vldA[KK], vldB[KK];
#pragma unroll
    for (int k = 0; k < KK; ++k) {
        int id = idsA[k];
        int sid = id < 0 ? 0 : id;
        vldA[k] = id < 0 ? 0.0f : 1.0f;
        pkA[k] = *(const vuint4*)(tab + rec_base(sid) + 8u * (unsigned int)h);
    }
#pragma unroll
    for (int k = 0; k < KK; ++k) {
        int id = idsB[k];
        int sid = id < 0 ? 0 : id;
        vldB[k] = id < 0 ? 0.0f : 1.0f;
        pkB[k] = *(const vuint4*)(tab + rec_base(sid) + 8u * (unsigned int)h);
    }

    int mlane = ((tid & 63) | 1);  // odd lane of the pair holds meta in .z

    // ---- pixel A ----
    {
        float a0 = 0.f, a1 = 0.f, a2 = 0.f, a3 = 0.f;
        float a4 = 0.f, a5 = 0.f, a6 = 0.f, a7 = 0.f;
        float T = 1.0f;
#pragma unroll
        for (int k = 0; k < KK; ++k) {
            unsigned int meta = (unsigned int)__shfl((int)pkA[k].z, mlane, 64);
            float ir2 = __uint_as_float((meta & 0xFFFFu) << 16);
            float s = __uint_as_float(meta & 0xFFFF0000u);
            float w = (1.0f - dsA[k] * ir2) * vldA[k];
            float as = (w * T) * s;
            T *= (1.0f - w);
            unsigned int px = pkA[k].x, py = pkA[k].y;
            a0 += as * (float)((int)(px << 24) >> 24);
            a1 += as * (float)((int)(px << 16) >> 24);
            a2 += as * (float)((int)(px << 8) >> 24);
            a3 += as * (float)((int)px >> 24);
            a4 += as * (float)((int)(py << 24) >> 24);
            a5 += as * (float)((int)(py << 16) >> 24);
            a6 += as * (float)((int)(py << 8) >> 24);
            a7 += as * (float)((int)py >> 24);
        }
        float* ob = out + (size_t)px0 * CC + 8 * h;
        vfloat4 r0 = {a0, a1, a2, a3};
        vfloat4 r1 = {a4, a5, a6, a7};
        __builtin_nontemporal_store(r0, (vfloat4*)ob);
        __builtin_nontemporal_store(r1, (vfloat4*)(ob + 4));
    }

    // ---- pixel B ----
    {
        float a0 = 0.f, a1 = 0.f, a2 = 0.f, a3 = 0.f;
        float a4 = 0.f, a5 = 0.f, a6 = 0.f, a7 = 0.f;
        float T = 1.0f;
#pragma unroll
        for (int k = 0; k < KK; ++k) {
            unsigned int meta = (unsigned int)__shfl((int)pkB[k].z, mlane, 64);
            float ir2 = __uint_as_float((meta & 0xFFFFu) << 16);
            float s = __uint_as_float(meta & 0xFFFF0000u);
            float w = (1.0f - dsB[k] * ir2) * vldB[k];
            float as = (w * T) * s;
            T *= (1.0f - w);
            unsigned int px = pkB[k].x, py = pkB[k].y;
            a0 += as * (float)((int)(px << 24) >> 24);
            a1 += as * (float)((int)(px << 16) >> 24);
            a2 += as * (float)((int)(px << 8) >> 24);
            a3 += as * (float)((int)px >> 24);
            a4 += as * (float)((int)(py << 24) >> 24);
            a5 += as * (float)((int)(py << 16) >> 24);
            a6 += as * (float)((int)(py << 8) >> 24);
            a7 += as * (float)((int)py >> 24);
        }
        float* ob = out + (size_t)px1 * CC + 8 * h;
        vfloat4 r0 = {a0, a1, a2, a3};
        vfloat4 r1 = {a4, a5, a6, a7};
        __builtin_nontemporal_store(r0, (vfloat4*)ob);
        __builtin_nontemporal_store(r1, (vfloat4*)(ob + 4));
    }
}

extern "C" void kernel_launch(void* const* d_in, const int* in_sizes, int n_in,
                              void* d_out, int out_size, void* d_ws, size_t ws_size,
                              hipStream_t stream) {
    const int* idx = (const int*)d_in[0];
    const float* dists = (const float*)d_in[1];
    const float* radii = (const float*)d_in[2];
    const float* features = (const float*)d_in[3];
    float* out = (float*)d_out;

    int P = in_sizes[2];            // 200000
    int npix = in_sizes[0] / KK;    // B*H*W = 1048576

    char* tab = (char*)d_ws;        // ceil(P/3)*64 = ~4.27MB

    prep_kernel<<<(P + 255) / 256, 256, 0, stream>>>(features, radii, tab, P);

    int nthreads = npix;            // 2 lanes/pair * 2 pixels/pair
    render_kernel<<<(nthreads + 255) / 256, 256, 0, stream>>>(
        idx, dists, tab, out, npix);
}

// Round 10
// 88.111 us; speedup vs baseline: 1.2353x; 1.2353x over previous
//
#include <hip/hip_runtime.h>

#define KK 8
#define CC 16

typedef int   vint4   __attribute__((ext_vector_type(4)));
typedef float vfloat4 __attribute__((ext_vector_type(4)));
typedef unsigned int vuint4 __attribute__((ext_vector_type(4)));

// Record: 20B = 16 x i8 features + meta dword {bf16 inv_r2 | bf16 scale<<16}.
// 3 records per 64B line (60B + 4B pad): a record NEVER straddles a line.
static __device__ __forceinline__ unsigned int rec_base(int p) {
    int grp = p / 3;          // magic-mul
    int lane = p - grp * 3;
    return (unsigned int)grp * 64u + (unsigned int)lane * 20u;
}

static __device__ __forceinline__ unsigned short f32_to_bf16(float x) {
    unsigned int b = __float_as_uint(x);
    unsigned int r = b + 0x7FFFu + ((b >> 16) & 1u);
    return (unsigned short)(r >> 16);
}

// ---- Pass 1 (only prep pass): per-point scale + quantize + pack ----
__global__ void prep_kernel(const float* __restrict__ f,
                            const float* __restrict__ radii,
                            char* __restrict__ tab, int P) {
    int p = blockIdx.x * blockDim.x + threadIdx.x;
    if (p >= P) return;
    float v[CC];
    float am = 1e-20f;
#pragma unroll
    for (int c = 0; c < CC; ++c) {
        v[c] = f[(size_t)c * P + p];
        am = fmaxf(am, fabsf(v[c]));
    }
    unsigned short sc_b = f32_to_bf16(am * (1.0f / 127.0f));
    float s = __uint_as_float((unsigned int)sc_b << 16);
    float qs = 1.0f / s;
    unsigned int w[4];
#pragma unroll
    for (int j = 0; j < 4; ++j) {
        int q0 = __float2int_rn(v[4 * j + 0] * qs); q0 = max(-127, min(127, q0));
        int q1 = __float2int_rn(v[4 * j + 1] * qs); q1 = max(-127, min(127, q1));
        int q2 = __float2int_rn(v[4 * j + 2] * qs); q2 = max(-127, min(127, q2));
        int q3 = __float2int_rn(v[4 * j + 3] * qs); q3 = max(-127, min(127, q3));
        w[j] = ((unsigned int)q0 & 0xFFu) | (((unsigned int)q1 & 0xFFu) << 8) |
               (((unsigned int)q2 & 0xFFu) << 16) | (((unsigned int)q3 & 0xFFu) << 24);
    }
    float r = radii[p];
    unsigned short ir2_b = f32_to_bf16(1.0f / (r * r));
    unsigned int meta = (unsigned int)ir2_b | ((unsigned int)sc_b << 16);
    char* rec = tab + rec_base(p);
    *(unsigned int*)(rec + 0) = w[0];
    *(unsigned int*)(rec + 4) = w[1];
    *(unsigned int*)(rec + 8) = w[2];
    *(unsigned int*)(rec + 12) = w[3];
    *(unsigned int*)(rec + 16) = meta;
}

// ---- Pass 2: render. 2 lanes per pixel (R6 layout, fully coalesced streams
// and stores); each lane-pair ALSO processes pixel pix + npix/2 (same wave-
// coalesced pattern, offset by half the image). 16 gathers in flight/thread.
__global__ void render_kernel(const int* __restrict__ idx,
                              const float* __restrict__ dists,
                              const char* __restrict__ tab,
                              float* __restrict__ out, int npix) {
    int tid = blockIdx.x * blockDim.x + threadIdx.x;
    int pixA = tid >> 1;
    int h = tid & 1;
    int half = npix >> 1;
    if (pixA >= half) return;
    int pixB = pixA + half;

    const vint4* ipa = (const vint4*)(idx + (size_t)pixA * KK);
    const vfloat4* dpa = (const vfloat4*)(dists + (size_t)pixA * KK);
    const vint4* ipb = (const vint4*)(idx + (size_t)pixB * KK);
    const vfloat4* dpb = (const vfloat4*)(dists + (size_t)pixB * KK);
    vint4 ia0 = __builtin_nontemporal_load(ipa);
    vint4 ia1 = __builtin_nontemporal_load(ipa + 1);
    vfloat4 da0 = __builtin_nontemporal_load(dpa);
    vfloat4 da1 = __builtin_nontemporal_load(dpa + 1);
    vint4 ib0 = __builtin_nontemporal_load(ipb);
    vint4 ib1 = __builtin_nontemporal_load(ipb + 1);
    vfloat4 db0 = __builtin_nontemporal_load(dpb);
    vfloat4 db1 = __builtin_nontemporal_load(dpb + 1);

    int idsA[KK] = {ia0.x, ia0.y, ia0.z, ia0.w, ia1.x, ia1.y, ia1.z, ia1.w};
    int idsB[KK] = {ib0.x, ib0.y, ib0.z, ib0.w, ib1.x, ib1.y, ib1.z, ib1.w};
    float dsA[KK] = {da0.x, da0.y, da0.z, da0.w, da1.x, da1.y, da1.z, da1.w};
    float dsB[KK] = {db0.x, db0.y, db0.z, db0.w, db1.x, db1.y, db1.z, db1.w};

    vuint4 pkA[KK], pkB[KK];
    float vldA[KK], vldB[KK];
#pragma unroll
    for (int k = 0; k < KK; ++k) {
        int id = idsA[k];
        int sid = id < 0 ? 0 : id;
        vldA[k] = id < 0 ? 0.0f : 1.0f;
        pkA[k] = *(const vuint4*)(tab + rec_base(sid) + 8u * (unsigned int)h);
    }
#pragma unroll
    for (int k = 0; k < KK; ++k) {
        int id = idsB[k];
        int sid = id < 0 ? 0 : id;
        vldB[k] = id < 0 ? 0.0f : 1.0f;
        pkB[k] = *(const vuint4*)(tab + rec_base(sid) + 8u * (unsigned int)h);
    }

    int mlane = ((tid & 63) | 1);  // odd lane of the pair holds meta in .z

    // ---- pixel A (pkB still in flight during this compute) ----
    {
        float a0 = 0.f, a1 = 0.f, a2 = 0.f, a3 = 0.f;
        float a4 = 0.f, a5 = 0.f, a6 = 0.f, a7 = 0.f;
        float T = 1.0f;
#pragma unroll
        for (int k = 0; k < KK; ++k) {
            unsigned int meta = (unsigned int)__shfl((int)pkA[k].z, mlane, 64);
            float ir2 = __uint_as_float((meta & 0xFFFFu) << 16);
            float s = __uint_as_float(meta & 0xFFFF0000u);
            float w = (1.0f - dsA[k] * ir2) * vldA[k];
            float as = (w * T) * s;
            T *= (1.0f - w);
            unsigned int px = pkA[k].x, py = pkA[k].y;
            a0 += as * (float)((int)(px << 24) >> 24);
            a1 += as * (float)((int)(px << 16) >> 24);
            a2 += as * (float)((int)(px << 8) >> 24);
            a3 += as * (float)((int)px >> 24);
            a4 += as * (float)((int)(py << 24) >> 24);
            a5 += as * (float)((int)(py << 16) >> 24);
            a6 += as * (float)((int)(py << 8) >> 24);
            a7 += as * (float)((int)py >> 24);
        }
        float* ob = out + (size_t)pixA * CC + 8 * h;
        vfloat4 r0 = {a0, a1, a2, a3};
        vfloat4 r1 = {a4, a5, a6, a7};
        __builtin_nontemporal_store(r0, (vfloat4*)ob);
        __builtin_nontemporal_store(r1, (vfloat4*)(ob + 4));
    }

    // ---- pixel B ----
    {
        float a0 = 0.f, a1 = 0.f, a2 = 0.f, a3 = 0.f;
        float a4 = 0.f, a5 = 0.f, a6 = 0.f, a7 = 0.f;
        float T = 1.0f;
#pragma unroll
        for (int k = 0; k < KK; ++k) {
            unsigned int meta = (unsigned int)__shfl((int)pkB[k].z, mlane, 64);
            float ir2 = __uint_as_float((meta & 0xFFFFu) << 16);
            float s = __uint_as_float(meta & 0xFFFF0000u);
            float w = (1.0f - dsB[k] * ir2) * vldB[k];
            float as = (w * T) * s;
            T *= (1.0f - w);
            unsigned int px = pkB[k].x, py = pkB[k].y;
            a0 += as * (float)((int)(px << 24) >> 24);
            a1 += as * (float)((int)(px << 16) >> 24);
            a2 += as * (float)((int)(px << 8) >> 24);
            a3 += as * (float)((int)px >> 24);
            a4 += as * (float)((int)(py << 24) >> 24);
            a5 += as * (float)((int)(py << 16) >> 24);
            a6 += as * (float)((int)(py << 8) >> 24);
            a7 += as * (float)((int)py >> 24);
        }
        float* ob = out + (size_t)pixB * CC + 8 * h;
        vfloat4 r0 = {a0, a1, a2, a3};
        vfloat4 r1 = {a4, a5, a6, a7};
        __builtin_nontemporal_store(r0, (vfloat4*)ob);
        __builtin_nontemporal_store(r1, (vfloat4*)(ob + 4));
    }
}

extern "C" void kernel_launch(void* const* d_in, const int* in_sizes, int n_in,
                              void* d_out, int out_size, void* d_ws, size_t ws_size,
                              hipStream_t stream) {
    const int* idx = (const int*)d_in[0];
    const float* dists = (const float*)d_in[1];
    const float* radii = (const float*)d_in[2];
    const float* features = (const float*)d_in[3];
    float* out = (float*)d_out;

    int P = in_sizes[2];            // 200000
    int npix = in_sizes[0] / KK;    // B*H*W = 1048576

    char* tab = (char*)d_ws;        // ceil(P/3)*64 = ~4.27MB

    prep_kernel<<<(P + 255) / 256, 256, 0, stream>>>(features, radii, tab, P);

    int nthreads = npix;            // (npix/2 pairs) * 2 lanes
    render_kernel<<<(nthreads + 255) / 256, 256, 0, stream>>>(
        idx, dists, tab, out, npix);
}

// Round 12
// 77.148 us; speedup vs baseline: 1.4108x; 1.1421x over previous
//
#include <hip/hip_runtime.h>

#define KK 8
#define CC 16

typedef int   vint4   __attribute__((ext_vector_type(4)));
typedef float vfloat4 __attribute__((ext_vector_type(4)));
typedef unsigned int vuint4 __attribute__((ext_vector_type(4)));

// Record: 20B = 16 x i8 features + meta dword {bf16 inv_r2 | bf16 scale<<16}.
// 3 records per 64B line (60B + 4B pad): a record NEVER straddles a line.
static __device__ __forceinline__ unsigned int rec_base(int p) {
    int grp = p / 3;          // magic-mul
    int lane = p - grp * 3;
    return (unsigned int)grp * 64u + (unsigned int)lane * 20u;
}

static __device__ __forceinline__ unsigned short f32_to_bf16(float x) {
    unsigned int b = __float_as_uint(x);
    unsigned int r = b + 0x7FFFu + ((b >> 16) & 1u);
    return (unsigned short)(r >> 16);
}

// Raw buffer resource: stride=0, num_records=bytes.
static __device__ __forceinline__ vint4 make_srsrc(const void* p, unsigned int bytes) {
    union { const void* p; unsigned long long u; } a;
    a.p = p;
    vint4 r;
    r.x = (int)(a.u & 0xFFFFFFFFull);
    r.y = (int)((a.u >> 32) & 0xFFFFull);
    r.z = (int)bytes;
    r.w = 0x00020000;
    return r;
}

// ---- Pass 1 (only prep pass): per-point scale + quantize + pack ----
__global__ void prep_kernel(const float* __restrict__ f,
                            const float* __restrict__ radii,
                            char* __restrict__ tab, int P) {
    int p = blockIdx.x * blockDim.x + threadIdx.x;
    if (p >= P) return;
    float v[CC];
    float am = 1e-20f;
#pragma unroll
    for (int c = 0; c < CC; ++c) {
        v[c] = f[(size_t)c * P + p];
        am = fmaxf(am, fabsf(v[c]));
    }
    unsigned short sc_b = f32_to_bf16(am * (1.0f / 127.0f));
    float s = __uint_as_float((unsigned int)sc_b << 16);
    float qs = 1.0f / s;
    unsigned int w[4];
#pragma unroll
    for (int j = 0; j < 4; ++j) {
        int q0 = __float2int_rn(v[4 * j + 0] * qs); q0 = max(-127, min(127, q0));
        int q1 = __float2int_rn(v[4 * j + 1] * qs); q1 = max(-127, min(127, q1));
        int q2 = __float2int_rn(v[4 * j + 2] * qs); q2 = max(-127, min(127, q2));
        int q3 = __float2int_rn(v[4 * j + 3] * qs); q3 = max(-127, min(127, q3));
        w[j] = ((unsigned int)q0 & 0xFFu) | (((unsigned int)q1 & 0xFFu) << 8) |
               (((unsigned int)q2 & 0xFFu) << 16) | (((unsigned int)q3 & 0xFFu) << 24);
    }
    float r = radii[p];
    unsigned short ir2_b = f32_to_bf16(1.0f / (r * r));
    unsigned int meta = (unsigned int)ir2_b | ((unsigned int)sc_b << 16);
    char* rec = tab + rec_base(p);
    *(unsigned int*)(rec + 0) = w[0];
    *(unsigned int*)(rec + 4) = w[1];
    *(unsigned int*)(rec + 8) = w[2];
    *(unsigned int*)(rec + 12) = w[3];
    *(unsigned int*)(rec + 16) = meta;
}

// ---- Pass 2: render. Forced MLP=16: all 16 gather dwordx4 held in registers
// (launch_bounds(256,2) -> 256-VGPR cap, no spills), single vmcnt(0) drain.
// Waits are spill-robust: vmcnt(4) only covers the OLDEST 4 ops (idx loads);
// final drain is vmcnt(0). 2 lanes/pixel; pair handles pixA and pixA+npix/2.
__global__ void __launch_bounds__(256, 2)
render_kernel(const int* __restrict__ idx,
              const float* __restrict__ dists,
              const char* __restrict__ tab,
              unsigned int tab_bytes,
              float* __restrict__ out, int npix) {
    int tid = blockIdx.x * blockDim.x + threadIdx.x;
    int pair = tid >> 1;
    int h = tid & 1;
    int half = npix >> 1;
    if (pair >= half) return;
    int pixA = pair, pixB = pair + half;

    vint4 rs_idx = make_srsrc(idx, (unsigned int)npix * 32u);
    vint4 rs_dst = make_srsrc(dists, (unsigned int)npix * 32u);
    vint4 rs_tab = make_srsrc(tab, tab_bytes);

    unsigned int aoff = (unsigned int)pixA * 32u;
    unsigned int boff = (unsigned int)pixB * 32u;

    vint4 iA0, iA1, iB0, iB1;
    vfloat4 dA0, dA1, dB0, dB1;
    // issue order matters for the counted wait: idx first (oldest), dists after
    asm volatile("buffer_load_dwordx4 %0, %1, %2, 0 offen nt" : "=&v"(iA0) : "v"(aoff), "s"(rs_idx));
    asm volatile("buffer_load_dwordx4 %0, %1, %2, 0 offen offset:16 nt" : "=&v"(iA1) : "v"(aoff), "s"(rs_idx));
    asm volatile("buffer_load_dwordx4 %0, %1, %2, 0 offen nt" : "=&v"(iB0) : "v"(boff), "s"(rs_idx));
    asm volatile("buffer_load_dwordx4 %0, %1, %2, 0 offen offset:16 nt" : "=&v"(iB1) : "v"(boff), "s"(rs_idx));
    asm volatile("buffer_load_dwordx4 %0, %1, %2, 0 offen nt" : "=&v"(dA0) : "v"(aoff), "s"(rs_dst));
    asm volatile("buffer_load_dwordx4 %0, %1, %2, 0 offen offset:16 nt" : "=&v"(dA1) : "v"(aoff), "s"(rs_dst));
    asm volatile("buffer_load_dwordx4 %0, %1, %2, 0 offen nt" : "=&v"(dB0) : "v"(boff), "s"(rs_dst));
    asm volatile("buffer_load_dwordx4 %0, %1, %2, 0 offen offset:16 nt" : "=&v"(dB1) : "v"(boff), "s"(rs_dst));

    // idx loads are the 4 OLDEST outstanding ops -> vmcnt(4) guarantees them
    // even if junior (spill/other) VMEM ops were appended after.
    asm volatile("s_waitcnt vmcnt(4)" ::: "memory");
    __builtin_amdgcn_sched_barrier(0);

    int idsA[KK] = {iA0.x, iA0.y, iA0.z, iA0.w, iA1.x, iA1.y, iA1.z, iA1.w};
    int idsB[KK] = {iB0.x, iB0.y, iB0.z, iB0.w, iB1.x, iB1.y, iB1.z, iB1.w};

    unsigned int voffA[KK], voffB[KK];
    float vldA[KK], vldB[KK];
#pragma unroll
    for (int k = 0; k < KK; ++k) {
        int id = idsA[k];
        int sid = id < 0 ? 0 : id;
        vldA[k] = id < 0 ? 0.0f : 1.0f;
        voffA[k] = rec_base(sid) + 8u * (unsigned int)h;
    }
#pragma unroll
    for (int k = 0; k < KK; ++k) {
        int id = idsB[k];
        int sid = id < 0 ? 0 : id;
        vldB[k] = id < 0 ? 0.0f : 1.0f;
        voffB[k] = rec_base(sid) + 8u * (unsigned int)h;
    }

    // 16 gathers issued back-to-back, ALL held in registers (MLP=16)
    vuint4 pkA[KK], pkB[KK];
#pragma unroll
    for (int k = 0; k < KK; ++k)
        asm volatile("buffer_load_dwordx4 %0, %1, %2, 0 offen" : "=&v"(pkA[k]) : "v"(voffA[k]), "s"(rs_tab));
#pragma unroll
    for (int k = 0; k < KK; ++k)
        asm volatile("buffer_load_dwordx4 %0, %1, %2, 0 offen" : "=&v"(pkB[k]) : "v"(voffB[k]), "s"(rs_tab));

    // Full drain: robust to any interleaved spill traffic.
    asm volatile("s_waitcnt vmcnt(0)" ::: "memory");
    __builtin_amdgcn_sched_barrier(0);

    float dsA[KK] = {dA0.x, dA0.y, dA0.z, dA0.w, dA1.x, dA1.y, dA1.z, dA1.w};
    float dsB[KK] = {dB0.x, dB0.y, dB0.z, dB0.w, dB1.x, dB1.y, dB1.z, dB1.w};

    int mlane = ((tid & 63) | 1);  // odd lane of the pair holds meta in .z

    // ---- pixel A ----
    {
        float a0 = 0.f, a1 = 0.f, a2 = 0.f, a3 = 0.f;
        float a4 = 0.f, a5 = 0.f, a6 = 0.f, a7 = 0.f;
        float T = 1.0f;
#pragma unroll
        for (int k = 0; k < KK; ++k) {
            unsigned int meta = (unsigned int)__shfl((int)pkA[k].z, mlane, 64);
            float ir2 = __uint_as_float((meta & 0xFFFFu) << 16);
            float s = __uint_as_float(meta & 0xFFFF0000u);
            float w = (1.0f - dsA[k] * ir2) * vldA[k];
            float as = (w * T) * s;
            T *= (1.0f - w);
            unsigned int px = pkA[k].x, py = pkA[k].y;
            a0 += as * (float)((int)(px << 24) >> 24);
            a1 += as * (float)((int)(px << 16) >> 24);
            a2 += as * (float)((int)(px << 8) >> 24);
            a3 += as * (float)((int)px >> 24);
            a4 += as * (float)((int)(py << 24) >> 24);
            a5 += as * (float)((int)(py << 16) >> 24);
            a6 += as * (float)((int)(py << 8) >> 24);
            a7 += as * (float)((int)py >> 24);
        }
        float* ob = out + (size_t)pixA * CC + 8 * h;
        vfloat4 r0 = {a0, a1, a2, a3};
        vfloat4 r1 = {a4, a5, a6, a7};
        __builtin_nontemporal_store(r0, (vfloat4*)ob);
        __builtin_nontemporal_store(r1, (vfloat4*)(ob + 4));
    }

    // ---- pixel B ----
    {
        float a0 = 0.f, a1 = 0.f, a2 = 0.f, a3 = 0.f;
        float a4 = 0.f, a5 = 0.f, a6 = 0.f, a7 = 0.f;
        float T = 1.0f;
#pragma unroll
        for (int k = 0; k < KK; ++k) {
            unsigned int meta = (unsigned int)__shfl((int)pkB[k].z, mlane, 64);
            float ir2 = __uint_as_float((meta & 0xFFFFu) << 16);
            float s = __uint_as_float(meta & 0xFFFF0000u);
            float w = (1.0f - dsB[k] * ir2) * vldB[k];
            float as = (w * T) * s;
            T *= (1.0f - w);
            unsigned int px = pkB[k].x, py = pkB[k].y;
            a0 += as * (float)((int)(px << 24) >> 24);
            a1 += as * (float)((int)(px << 16) >> 24);
            a2 += as * (float)((int)(px << 8) >> 24);
            a3 += as * (float)((int)px >> 24);
            a4 += as * (float)((int)(py << 24) >> 24);
            a5 += as * (float)((int)(py << 16) >> 24);
            a6 += as * (float)((int)(py << 8) >> 24);
            a7 += as * (float)((int)py >> 24);
        }
        float* ob = out + (size_t)pixB * CC + 8 * h;
        vfloat4 r0 = {a0, a1, a2, a3};
        vfloat4 r1 = {a4, a5, a6, a7};
        __builtin_nontemporal_store(r0, (vfloat4*)ob);
        __builtin_nontemporal_store(r1, (vfloat4*)(ob + 4));
    }
}

extern "C" void kernel_launch(void* const* d_in, const int* in_sizes, int n_in,
                              void* d_out, int out_size, void* d_ws, size_t ws_size,
                              hipStream_t stream) {
    const int* idx = (const int*)d_in[0];
    const float* dists = (const float*)d_in[1];
    const float* radii = (const float*)d_in[2];
    const float* features = (const float*)d_in[3];
    float* out = (float*)d_out;

    int P = in_sizes[2];            // 200000
    int npix = in_sizes[0] / KK;    // B*H*W = 1048576

    char* tab = (char*)d_ws;        // ceil(P/3)*64 = ~4.27MB
    unsigned int tab_bytes = (unsigned int)(((P + 2) / 3) * 64);

    prep_kernel<<<(P + 255) / 256, 256, 0, stream>>>(features, radii, tab, P);

    int nthreads = npix;            // (npix/2 pairs) * 2 lanes
    render_kernel<<<(nthreads + 255) / 256, 256, 0, stream>>>(
        idx, dists, tab, tab_bytes, out, npix);
}